// Round 1
// baseline (309.320 us; speedup 1.0000x reference)
//
#include <hip/hip_runtime.h>
#include <stdint.h>
#include <stddef.h>

// Problem constants
#define B_  16
#define C_  512
#define N_  1024    // H*W = 32*32
#define NH  8
#define HD  64

typedef __attribute__((ext_vector_type(8))) short bf16x8;
typedef __attribute__((ext_vector_type(4))) float f32x4;

__device__ __forceinline__ short f2bf(float f) {
    unsigned u = __builtin_bit_cast(unsigned, f);
    unsigned r = (u + 0x7fffu + ((u >> 16) & 1u)) >> 16;   // RNE
    return (short)(unsigned short)r;
}
__device__ __forceinline__ float bf2f(short s) {
    unsigned u = ((unsigned)(unsigned short)s) << 16;
    return __builtin_bit_cast(float, u);
}

#define MFMA16(a, b, c) __builtin_amdgcn_mfma_f32_16x16x32_bf16((a), (b), (c), 0, 0, 0)

typedef __attribute__((address_space(3))) unsigned int lds_u32;
typedef __attribute__((address_space(1))) unsigned int glb_u32;
// dest = wave-uniform LDS base + lane*16 (m104); global src is per-lane.
__device__ __forceinline__ void gload16(const void* g, void* l) {
    __builtin_amdgcn_global_load_lds((const glb_u32*)g, (lds_u32*)l, 16, 0, 0);
}

// ---------------------------------------------------------------- weights cast
// src (K=512, J) fp32 row-major  ->  dst (J, 512) bf16 row-major  (B^T layout)
__global__ void k_transpose_cast(const float* __restrict__ src, short* __restrict__ dst, int J) {
    int idx = blockIdx.x * 256 + threadIdx.x;           // over J*512
    int j = idx >> 9, k = idx & 511;
    dst[idx] = f2bf(src[(size_t)k * J + j]);
}

// ---------------------------------------------------------------- rope table
__global__ void k_rope_table(float* __restrict__ cosT, float* __restrict__ sinT) {
    int idx = blockIdx.x * 256 + threadIdx.x;           // N_*64
    if (idx >= N_ * 64) return;
    int n = idx >> 6, j = idx & 63;
    int y = n >> 5, xq = n & 31;
    int pos = (j < 32) ? y : xq;
    int i = j & 15;                                     // quarter = 16
    float freq = (float)pos * powf(100.0f, -(float)i * (1.0f / 16.0f));
    cosT[idx] = cosf(freq);
    sinT[idx] = sinf(freq);
}

// ---------------------------------------------------------------- time MLP
__global__ __launch_bounds__(512) void k_time_mlp(
        const float* __restrict__ temb, const float* __restrict__ w1, const float* __restrict__ b1,
        const float* __restrict__ w2, const float* __restrict__ b2, float* __restrict__ gbout) {
    __shared__ float tl[512];
    __shared__ float hl[512];
    int b = blockIdx.x, tid = threadIdx.x;
    tl[tid] = temb[b * 512 + tid];
    __syncthreads();
    float acc = b1[tid];
#pragma unroll 8
    for (int k = 0; k < 512; k++) acc += tl[k] * w1[(size_t)k * 512 + tid];
    hl[tid] = acc / (1.0f + __expf(-acc));              // silu
    __syncthreads();
    float a0 = b2[tid], a1 = b2[tid + 512];
#pragma unroll 8
    for (int k = 0; k < 512; k++) {
        float hk = hl[k];
        a0 += hk * w2[(size_t)k * 1024 + tid];
        a1 += hk * w2[(size_t)k * 1024 + tid + 512];
    }
    gbout[b * 1024 + tid] = a0;
    gbout[b * 1024 + 512 + tid] = a1;
}

// ---------------------------------------------------------------- AdaCLN -> tokens bf16 (B,N,C)
__global__ __launch_bounds__(256) void k_adacln(
        const float* __restrict__ x, const float* __restrict__ gb, short* __restrict__ tokens) {
    int b = blockIdx.y, n0 = blockIdx.x * 64;
    int tid = threadIdx.x, pix = tid & 63, sl = tid >> 6;
    const float* xb = x + (size_t)b * C_ * N_;
    __shared__ float rs[4][64], rq[4][64], mean_s[64], rstd_s[64];
    __shared__ float xs[64][65];

    float sum = 0.f, sq = 0.f;
    for (int ci = 0; ci < 128; ci++) {
        int c = sl * 128 + ci;
        float v = xb[(size_t)c * N_ + n0 + pix];
        sum += v; sq += v * v;
    }
    rs[sl][pix] = sum; rq[sl][pix] = sq;
    __syncthreads();
    if (tid < 64) {
        float s1 = rs[0][tid] + rs[1][tid] + rs[2][tid] + rs[3][tid];
        float s2 = rq[0][tid] + rq[1][tid] + rq[2][tid] + rq[3][tid];
        float mu = s1 * (1.0f / 512.0f);
        float var = s2 * (1.0f / 512.0f) - mu * mu;
        mean_s[tid] = mu;
        rstd_s[tid] = rsqrtf(var + 1e-6f);
    }
    const float* gam = gb + b * 1024;
    const float* bet = gam + 512;
    int ch = tid & 7;
    for (int ct = 0; ct < 8; ct++) {
        __syncthreads();
        for (int it = 0; it < 16; it++) {
            int cl = it * 4 + sl;
            xs[cl][pix] = xb[(size_t)(ct * 64 + cl) * N_ + n0 + pix];
        }
        __syncthreads();
#pragma unroll
        for (int pp = 0; pp < 2; pp++) {
            int p = pp * 32 + (tid >> 3);
            float mu = mean_s[p], rt = rstd_s[p];
            bf16x8 ov;
#pragma unroll
            for (int j = 0; j < 8; j++) {
                int c = ct * 64 + ch * 8 + j;
                float v = (xs[ch * 8 + j][p] - mu) * rt * (1.0f + gam[c]) + bet[c];
                ov[j] = f2bf(v);
            }
            *(bf16x8*)(tokens + ((size_t)(b * N_ + n0 + p)) * C_ + ct * 64 + ch * 8) = ov;
        }
    }
}

// ---------------------------------------------------------------- QKV GEMM (M=16384,N=1536,K=512)
// A = tokens (row-major), Bt = qkv_wT (1536,512). Epilogue scatters to q/k (B,h,N,d), v^T (B,h,d,N).
__global__ __launch_bounds__(256) void k_gemm_qkv(
        const short* __restrict__ A, const short* __restrict__ Bt,
        short* __restrict__ qr, short* __restrict__ kr, short* __restrict__ vt) {
    __shared__ short Asm[128 * 32];
    __shared__ short Bsm[128 * 32];
    int tid = threadIdx.x, wv = tid >> 6, ln = tid & 63;
    int wr = wv >> 1, wc = wv & 1, lr = ln & 15, lg = ln >> 4;
    const short* Ab = A + (size_t)blockIdx.y * 128 * 512;
    const short* Bb = Bt + (size_t)blockIdx.x * 128 * 512;
    f32x4 acc[4][4] = {};
    int srow = ln >> 2, sch = ln & 3;
    for (int kb = 0; kb < 512; kb += 32) {
        int r0 = wv * 32;
        const short* ga = Ab + (size_t)(r0 + srow) * 512 + kb + sch * 8;
        gload16(ga, (void*)(Asm + r0 * 32));
        gload16(ga + 16 * 512, (void*)(Asm + (r0 + 16) * 32));
        const short* gbp = Bb + (size_t)(r0 + srow) * 512 + kb + sch * 8;
        gload16(gbp, (void*)(Bsm + r0 * 32));
        gload16(gbp + 16 * 512, (void*)(Bsm + (r0 + 16) * 32));
        __syncthreads();
        bf16x8 af[4], bfr[4];
#pragma unroll
        for (int m = 0; m < 4; m++) af[m] = *(const bf16x8*)(Asm + (wr * 64 + m * 16 + lr) * 32 + lg * 8);
#pragma unroll
        for (int f = 0; f < 4; f++) bfr[f] = *(const bf16x8*)(Bsm + (wc * 64 + f * 16 + lr) * 32 + lg * 8);
#pragma unroll
        for (int m = 0; m < 4; m++)
#pragma unroll
            for (int f = 0; f < 4; f++)
                acc[m][f] = MFMA16(af[m], bfr[f], acc[m][f]);
        __syncthreads();
    }
    int mbase = blockIdx.y * 128, jbase = blockIdx.x * 128;
#pragma unroll
    for (int m = 0; m < 4; m++) {
        int gmb = mbase + wr * 64 + m * 16 + lg * 4;
#pragma unroll
        for (int f = 0; f < 4; f++) {
            int gj = jbase + wc * 64 + f * 16 + lr;
            int sec = gj >> 9, wn = gj & 511;
            int h = wn >> 6, d = wn & 63;
#pragma unroll
            for (int r = 0; r < 4; r++) {
                int gm = gmb + r;
                int b = gm >> 10, n = gm & 1023;
                short v = f2bf(acc[m][f][r]);
                if (sec == 0)      qr[(((size_t)b * NH + h) * N_ + n) * HD + d] = v;
                else if (sec == 1) kr[(((size_t)b * NH + h) * N_ + n) * HD + d] = v;
                else               vt[(((size_t)b * NH + h) * HD + d) * N_ + n] = v;
            }
        }
    }
}

// ---------------------------------------------------------------- RoPE in-place on q,k
__global__ void k_rope(short* __restrict__ qr, short* __restrict__ kr,
                       const float* __restrict__ cosT, const float* __restrict__ sinT) {
    const int total = 2 * B_ * NH * N_ * 32;            // pairs
    for (int idx = blockIdx.x * blockDim.x + threadIdx.x; idx < total; idx += gridDim.x * blockDim.x) {
        int p = idx & 31;
        int row = idx >> 5;                              // 0..262143
        short* buf = (row & 131072) ? kr : qr;
        int rr = row & 131071;
        int n = rr & 1023;
        size_t base = (size_t)rr * 64;
        float a = bf2f(buf[base + p]), b = bf2f(buf[base + p + 32]);
        float c0 = cosT[n * 64 + p], s0 = sinT[n * 64 + p];
        float c1 = cosT[n * 64 + p + 32], s1 = sinT[n * 64 + p + 32];
        buf[base + p]      = f2bf(a * c0 - b * s0);
        buf[base + p + 32] = f2bf(b * c1 + a * s1);
    }
}

// ---------------------------------------------------------------- flash attention
// grid (16 q-tiles, 128 bh); 4 waves x 16 q-rows; K/V tiles 64 staged in LDS (stride 88 bf16).
__global__ __launch_bounds__(256) void k_flash(
        const short* __restrict__ qr, const short* __restrict__ kr, const short* __restrict__ vt,
        short* __restrict__ attn_out) {
    __shared__ short Ks[64 * 88];
    __shared__ short Vs[64 * 88];
    __shared__ short Ps[4][16 * 88];
    int bh = blockIdx.y, b = bh >> 3, h = bh & 7;
    int tid = threadIdx.x, wv = tid >> 6, ln = tid & 63, lr = ln & 15, lg = ln >> 4;
    const short* Qb = qr + ((size_t)bh * N_ + blockIdx.x * 64) * HD;
    const short* Kb = kr + (size_t)bh * N_ * HD;
    const short* Vb = vt + (size_t)bh * HD * N_;

    bf16x8 qf0 = *(const bf16x8*)(Qb + (wv * 16 + lr) * 64 + lg * 8);
    bf16x8 qf1 = *(const bf16x8*)(Qb + (wv * 16 + lr) * 64 + 32 + lg * 8);

    float m_r[4], l_r[4];
    f32x4 ao[4] = {};
#pragma unroll
    for (int r = 0; r < 4; r++) { m_r[r] = -1e30f; l_r[r] = 0.f; }

    for (int kt = 0; kt < 16; kt++) {
        __syncthreads();
#pragma unroll
        for (int p = 0; p < 2; p++) {
            int flat = p * 256 + tid, rw = flat >> 3, ch = flat & 7;
            *(bf16x8*)(Ks + rw * 88 + ch * 8) = *(const bf16x8*)(Kb + (size_t)(kt * 64 + rw) * 64 + ch * 8);
            *(bf16x8*)(Vs + rw * 88 + ch * 8) = *(const bf16x8*)(Vb + (size_t)rw * N_ + kt * 64 + ch * 8);
        }
        __syncthreads();

        f32x4 sA[4];
#pragma unroll
        for (int f = 0; f < 4; f++) {
            f32x4 s = {};
            bf16x8 kf0 = *(const bf16x8*)(Ks + (f * 16 + lr) * 88 + lg * 8);
            bf16x8 kf1 = *(const bf16x8*)(Ks + (f * 16 + lr) * 88 + 32 + lg * 8);
            s = MFMA16(qf0, kf0, s);
            s = MFMA16(qf1, kf1, s);
            sA[f] = s;
        }
        float alpha_r[4], pvv[4][4];
#pragma unroll
        for (int r = 0; r < 4; r++) {
            float s0 = sA[0][r] * 0.125f, s1 = sA[1][r] * 0.125f;
            float s2 = sA[2][r] * 0.125f, s3 = sA[3][r] * 0.125f;
            float mx = fmaxf(fmaxf(s0, s1), fmaxf(s2, s3));
            mx = fmaxf(mx, __shfl_xor(mx, 1, 16));
            mx = fmaxf(mx, __shfl_xor(mx, 2, 16));
            mx = fmaxf(mx, __shfl_xor(mx, 4, 16));
            mx = fmaxf(mx, __shfl_xor(mx, 8, 16));
            float mnew = fmaxf(m_r[r], mx);
            float al = __expf(m_r[r] - mnew);
            float p0 = __expf(s0 - mnew), p1 = __expf(s1 - mnew);
            float p2 = __expf(s2 - mnew), p3 = __expf(s3 - mnew);
            float rsum = p0 + p1 + p2 + p3;
            rsum += __shfl_xor(rsum, 1, 16);
            rsum += __shfl_xor(rsum, 2, 16);
            rsum += __shfl_xor(rsum, 4, 16);
            rsum += __shfl_xor(rsum, 8, 16);
            l_r[r] = l_r[r] * al + rsum;
            m_r[r] = mnew;
            alpha_r[r] = al;
            pvv[0][r] = p0; pvv[1][r] = p1; pvv[2][r] = p2; pvv[3][r] = p3;
        }
#pragma unroll
        for (int df = 0; df < 4; df++)
#pragma unroll
            for (int r = 0; r < 4; r++) ao[df][r] *= alpha_r[r];

        short* Pw = &Ps[wv][0];
#pragma unroll
        for (int f = 0; f < 4; f++)
#pragma unroll
            for (int r = 0; r < 4; r++)
                Pw[(lg * 4 + r) * 88 + f * 16 + lr] = f2bf(pvv[f][r]);

        bf16x8 pa0 = *(const bf16x8*)(Pw + lr * 88 + lg * 8);
        bf16x8 pa1 = *(const bf16x8*)(Pw + lr * 88 + 32 + lg * 8);
#pragma unroll
        for (int df = 0; df < 4; df++) {
            bf16x8 v0 = *(const bf16x8*)(Vs + (df * 16 + lr) * 88 + lg * 8);
            bf16x8 v1 = *(const bf16x8*)(Vs + (df * 16 + lr) * 88 + 32 + lg * 8);
            ao[df] = MFMA16(pa0, v0, ao[df]);
            ao[df] = MFMA16(pa1, v1, ao[df]);
        }
    }
    size_t ob = ((size_t)b * N_ + blockIdx.x * 64 + wv * 16) * 512 + h * 64;
#pragma unroll
    for (int r = 0; r < 4; r++) {
        float inv = 1.0f / l_r[r];
        int n_loc = lg * 4 + r;
#pragma unroll
        for (int df = 0; df < 4; df++)
            attn_out[ob + (size_t)n_loc * 512 + df * 16 + lr] = f2bf(ao[df][r] * inv);
    }
}

// ---------------------------------------------------------------- out proj (transposed: M=channels)
// C[c][t] = sum_k out_wT[c][k] * attn[t][k];  out[b][c][n] = C + bias[c] + x[b][c][n]
__global__ __launch_bounds__(256) void k_gemm_out(
        const short* __restrict__ A, const short* __restrict__ Bt,
        const float* __restrict__ x, const float* __restrict__ obias, float* __restrict__ out) {
    __shared__ short Asm[128 * 32];
    __shared__ short Bsm[128 * 32];
    int tid = threadIdx.x, wv = tid >> 6, ln = tid & 63;
    int wr = wv >> 1, wc = wv & 1, lr = ln & 15, lg = ln >> 4;
    const short* Ab = A + (size_t)blockIdx.y * 128 * 512;
    const short* Bb = Bt + (size_t)blockIdx.x * 128 * 512;
    f32x4 acc[4][4] = {};
    int srow = ln >> 2, sch = ln & 3;
    for (int kb = 0; kb < 512; kb += 32) {
        int r0 = wv * 32;
        const short* ga = Ab + (size_t)(r0 + srow) * 512 + kb + sch * 8;
        gload16(ga, (void*)(Asm + r0 * 32));
        gload16(ga + 16 * 512, (void*)(Asm + (r0 + 16) * 32));
        const short* gbp = Bb + (size_t)(r0 + srow) * 512 + kb + sch * 8;
        gload16(gbp, (void*)(Bsm + r0 * 32));
        gload16(gbp + 16 * 512, (void*)(Bsm + (r0 + 16) * 32));
        __syncthreads();
        bf16x8 af[4], bfr[4];
#pragma unroll
        for (int m = 0; m < 4; m++) af[m] = *(const bf16x8*)(Asm + (wr * 64 + m * 16 + lr) * 32 + lg * 8);
#pragma unroll
        for (int f = 0; f < 4; f++) bfr[f] = *(const bf16x8*)(Bsm + (wc * 64 + f * 16 + lr) * 32 + lg * 8);
#pragma unroll
        for (int m = 0; m < 4; m++)
#pragma unroll
            for (int f = 0; f < 4; f++)
                acc[m][f] = MFMA16(af[m], bfr[f], acc[m][f]);
        __syncthreads();
    }
    int cb = blockIdx.y * 128 + wr * 64, tb = blockIdx.x * 128 + wc * 64;
#pragma unroll
    for (int m = 0; m < 4; m++) {
#pragma unroll
        for (int f = 0; f < 4; f++) {
            int gt = tb + f * 16 + lr;
            int b = gt >> 10, n = gt & 1023;
#pragma unroll
            for (int r = 0; r < 4; r++) {
                int gc = cb + m * 16 + lg * 4 + r;
                size_t ad = ((size_t)b * C_ + gc) * N_ + n;
                out[ad] = acc[m][f][r] + obias[gc] + x[ad];
            }
        }
    }
}

// ---------------------------------------------------------------- launch
extern "C" void kernel_launch(void* const* d_in, const int* in_sizes, int n_in,
                              void* d_out, int out_size, void* d_ws, size_t ws_size,
                              hipStream_t stream) {
    const float* x     = (const float*)d_in[0];
    const float* temb  = (const float*)d_in[1];
    const float* tm_w1 = (const float*)d_in[2];
    const float* tm_b1 = (const float*)d_in[3];
    const float* tm_w2 = (const float*)d_in[4];
    const float* tm_b2 = (const float*)d_in[5];
    const float* qkv_w = (const float*)d_in[6];
    const float* out_w = (const float*)d_in[7];
    const float* out_b = (const float*)d_in[8];
    float* out = (float*)d_out;

    char* ws = (char*)d_ws;
    short* qkvwT  = (short*)(ws);                 // 1536*512*2  = 1,572,864
    short* outwT  = (short*)(ws + 1572864);       //  512*512*2  =   524,288
    float* cosT   = (float*)(ws + 2097152);       // 1024*64*4   =   262,144
    float* sinT   = (float*)(ws + 2359296);
    float* gb     = (float*)(ws + 2621440);       // 16*1024*4
    short* tokens = (short*)(ws + 2686976);       // 16384*512*2 = 16,777,216 (also attn_out)
    short* qr     = (short*)(ws + 19464192);      // 16,777,216
    short* kr     = (short*)(ws + 36241408);
    short* vt     = (short*)(ws + 53018624);      // end ~66.6 MB
    short* attn   = tokens;                        // tokens dead after k_gemm_qkv

    k_transpose_cast<<<dim3(3072), dim3(256), 0, stream>>>(qkv_w, qkvwT, 1536);
    k_transpose_cast<<<dim3(1024), dim3(256), 0, stream>>>(out_w, outwT, 512);
    k_rope_table<<<dim3(256), dim3(256), 0, stream>>>(cosT, sinT);
    k_time_mlp<<<dim3(16), dim3(512), 0, stream>>>(temb, tm_w1, tm_b1, tm_w2, tm_b2, gb);
    k_adacln<<<dim3(16, 16), dim3(256), 0, stream>>>(x, gb, tokens);
    k_gemm_qkv<<<dim3(12, 128), dim3(256), 0, stream>>>(tokens, qkvwT, qr, kr, vt);
    k_rope<<<dim3(4096), dim3(256), 0, stream>>>(qr, kr, cosT, sinT);
    k_flash<<<dim3(16, 128), dim3(256), 0, stream>>>(qr, kr, vt, attn);
    k_gemm_out<<<dim3(128, 4), dim3(256), 0, stream>>>(outwT, attn, x, out_b, out);
}

// Round 3
// 276.372 us; speedup vs baseline: 1.1192x; 1.1192x over previous
//
#include <hip/hip_runtime.h>
#include <stdint.h>
#include <stddef.h>

// Problem constants
#define B_  16
#define C_  512
#define N_  1024    // H*W = 32*32
#define NH  8
#define HD  64

typedef __attribute__((ext_vector_type(8))) short bf16x8;
typedef __attribute__((ext_vector_type(4))) float f32x4;

__device__ __forceinline__ short f2bf(float f) {
    unsigned u = __builtin_bit_cast(unsigned, f);
    unsigned r = (u + 0x7fffu + ((u >> 16) & 1u)) >> 16;   // RNE
    return (short)(unsigned short)r;
}
__device__ __forceinline__ float bf2f(short s) {
    unsigned u = ((unsigned)(unsigned short)s) << 16;
    return __builtin_bit_cast(float, u);
}
__device__ __forceinline__ unsigned pack2(float lo, float hi) {
    return ((unsigned)(unsigned short)f2bf(hi) << 16) | (unsigned)(unsigned short)f2bf(lo);
}

#define MFMA16(a, b, c) __builtin_amdgcn_mfma_f32_16x16x32_bf16((a), (b), (c), 0, 0, 0)

typedef __attribute__((address_space(3))) unsigned int lds_u32;
typedef __attribute__((address_space(1))) unsigned int glb_u32;
// dest = wave-uniform LDS base + lane*16 (m104); global src is per-lane.
__device__ __forceinline__ void gload16(const void* g, void* l) {
    __builtin_amdgcn_global_load_lds((const glb_u32*)g, (lds_u32*)l, 16, 0, 0);
}

// ---------------------------------------------------------------- weights cast
// src (K=512, J) fp32 row-major  ->  dst (J, 512) bf16 row-major  (B^T layout)
__global__ void k_transpose_cast(const float* __restrict__ src, short* __restrict__ dst, int J) {
    int idx = blockIdx.x * 256 + threadIdx.x;           // over J*512
    int j = idx >> 9, k = idx & 511;
    dst[idx] = f2bf(src[(size_t)k * J + j]);
}

// ---------------------------------------------------------------- rope table
__global__ void k_rope_table(float* __restrict__ cosT, float* __restrict__ sinT) {
    int idx = blockIdx.x * 256 + threadIdx.x;           // N_*64
    if (idx >= N_ * 64) return;
    int n = idx >> 6, j = idx & 63;
    int y = n >> 5, xq = n & 31;
    int pos = (j < 32) ? y : xq;
    int i = j & 15;                                     // quarter = 16
    float freq = (float)pos * powf(100.0f, -(float)i * (1.0f / 16.0f));
    cosT[idx] = cosf(freq);
    sinT[idx] = sinf(freq);
}

// ---------------------------------------------------------------- time MLP
__global__ __launch_bounds__(512) void k_time_mlp(
        const float* __restrict__ temb, const float* __restrict__ w1, const float* __restrict__ b1,
        const float* __restrict__ w2, const float* __restrict__ b2, float* __restrict__ gbout) {
    __shared__ float tl[512];
    __shared__ float hl[512];
    int b = blockIdx.x, tid = threadIdx.x;
    tl[tid] = temb[b * 512 + tid];
    __syncthreads();
    float acc = b1[tid];
#pragma unroll 8
    for (int k = 0; k < 512; k++) acc += tl[k] * w1[(size_t)k * 512 + tid];
    hl[tid] = acc / (1.0f + __expf(-acc));              // silu
    __syncthreads();
    float a0 = b2[tid], a1 = b2[tid + 512];
#pragma unroll 8
    for (int k = 0; k < 512; k++) {
        float hk = hl[k];
        a0 += hk * w2[(size_t)k * 1024 + tid];
        a1 += hk * w2[(size_t)k * 1024 + tid + 512];
    }
    gbout[b * 1024 + tid] = a0;
    gbout[b * 1024 + 512 + tid] = a1;
}

// ---------------------------------------------------------------- AdaCLN -> tokens bf16 (B,N,C)
__global__ __launch_bounds__(256) void k_adacln(
        const float* __restrict__ x, const float* __restrict__ gb, short* __restrict__ tokens) {
    int b = blockIdx.y, n0 = blockIdx.x * 64;
    int tid = threadIdx.x, pix = tid & 63, sl = tid >> 6;
    const float* xb = x + (size_t)b * C_ * N_;
    __shared__ float rs[4][64], rq[4][64], mean_s[64], rstd_s[64];
    __shared__ float xs[64][65];

    float sum = 0.f, sq = 0.f;
    for (int ci = 0; ci < 128; ci++) {
        int c = sl * 128 + ci;
        float v = xb[(size_t)c * N_ + n0 + pix];
        sum += v; sq += v * v;
    }
    rs[sl][pix] = sum; rq[sl][pix] = sq;
    __syncthreads();
    if (tid < 64) {
        float s1 = rs[0][tid] + rs[1][tid] + rs[2][tid] + rs[3][tid];
        float s2 = rq[0][tid] + rq[1][tid] + rq[2][tid] + rq[3][tid];
        float mu = s1 * (1.0f / 512.0f);
        float var = s2 * (1.0f / 512.0f) - mu * mu;
        mean_s[tid] = mu;
        rstd_s[tid] = rsqrtf(var + 1e-6f);
    }
    const float* gam = gb + b * 1024;
    const float* bet = gam + 512;
    int ch = tid & 7;
    for (int ct = 0; ct < 8; ct++) {
        __syncthreads();
        for (int it = 0; it < 16; it++) {
            int cl = it * 4 + sl;
            xs[cl][pix] = xb[(size_t)(ct * 64 + cl) * N_ + n0 + pix];
        }
        __syncthreads();
#pragma unroll
        for (int pp = 0; pp < 2; pp++) {
            int p = pp * 32 + (tid >> 3);
            float mu = mean_s[p], rt = rstd_s[p];
            bf16x8 ov;
#pragma unroll
            for (int j = 0; j < 8; j++) {
                int c = ct * 64 + ch * 8 + j;
                float v = (xs[ch * 8 + j][p] - mu) * rt * (1.0f + gam[c]) + bet[c];
                ov[j] = f2bf(v);
            }
            *(bf16x8*)(tokens + ((size_t)(b * N_ + n0 + p)) * C_ + ct * 64 + ch * 8) = ov;
        }
    }
}

// ---------------------------------------------------------------- QKV GEMM (M=16384,N=1536,K=512)
__global__ __launch_bounds__(256) void k_gemm_qkv(
        const short* __restrict__ A, const short* __restrict__ Bt,
        short* __restrict__ qr, short* __restrict__ kr, short* __restrict__ vt) {
    __shared__ short Asm[128 * 32];
    __shared__ short Bsm[128 * 32];
    int tid = threadIdx.x, wv = tid >> 6, ln = tid & 63;
    int wr = wv >> 1, wc = wv & 1, lr = ln & 15, lg = ln >> 4;
    const short* Ab = A + (size_t)blockIdx.y * 128 * 512;
    const short* Bb = Bt + (size_t)blockIdx.x * 128 * 512;
    f32x4 acc[4][4] = {};
    int srow = ln >> 2, sch = ln & 3;
    for (int kb = 0; kb < 512; kb += 32) {
        int r0 = wv * 32;
        const short* ga = Ab + (size_t)(r0 + srow) * 512 + kb + sch * 8;
        gload16(ga, (void*)(Asm + r0 * 32));
        gload16(ga + 16 * 512, (void*)(Asm + (r0 + 16) * 32));
        const short* gbp = Bb + (size_t)(r0 + srow) * 512 + kb + sch * 8;
        gload16(gbp, (void*)(Bsm + r0 * 32));
        gload16(gbp + 16 * 512, (void*)(Bsm + (r0 + 16) * 32));
        __syncthreads();
        bf16x8 af[4], bfr[4];
#pragma unroll
        for (int m = 0; m < 4; m++) af[m] = *(const bf16x8*)(Asm + (wr * 64 + m * 16 + lr) * 32 + lg * 8);
#pragma unroll
        for (int f = 0; f < 4; f++) bfr[f] = *(const bf16x8*)(Bsm + (wc * 64 + f * 16 + lr) * 32 + lg * 8);
#pragma unroll
        for (int m = 0; m < 4; m++)
#pragma unroll
            for (int f = 0; f < 4; f++)
                acc[m][f] = MFMA16(af[m], bfr[f], acc[m][f]);
        __syncthreads();
    }
    int mbase = blockIdx.y * 128, jbase = blockIdx.x * 128;
#pragma unroll
    for (int m = 0; m < 4; m++) {
        int gmb = mbase + wr * 64 + m * 16 + lg * 4;
#pragma unroll
        for (int f = 0; f < 4; f++) {
            int gj = jbase + wc * 64 + f * 16 + lr;
            int sec = gj >> 9, wn = gj & 511;
            int h = wn >> 6, d = wn & 63;
#pragma unroll
            for (int r = 0; r < 4; r++) {
                int gm = gmb + r;
                int b = gm >> 10, n = gm & 1023;
                short v = f2bf(acc[m][f][r]);
                if (sec == 0)      qr[(((size_t)b * NH + h) * N_ + n) * HD + d] = v;
                else if (sec == 1) kr[(((size_t)b * NH + h) * N_ + n) * HD + d] = v;
                else               vt[(((size_t)b * NH + h) * HD + d) * N_ + n] = v;
            }
        }
    }
}

// ---------------------------------------------------------------- RoPE in-place on q,k
__global__ void k_rope(short* __restrict__ qr, short* __restrict__ kr,
                       const float* __restrict__ cosT, const float* __restrict__ sinT) {
    const int total = 2 * B_ * NH * N_ * 32;            // pairs
    for (int idx = blockIdx.x * blockDim.x + threadIdx.x; idx < total; idx += gridDim.x * blockDim.x) {
        int p = idx & 31;
        int row = idx >> 5;                              // 0..262143
        short* buf = (row & 131072) ? kr : qr;
        int rr = row & 131071;
        int n = rr & 1023;
        size_t base = (size_t)rr * 64;
        float a = bf2f(buf[base + p]), b = bf2f(buf[base + p + 32]);
        float c0 = cosT[n * 64 + p], s0 = sinT[n * 64 + p];
        float c1 = cosT[n * 64 + p + 32], s1 = sinT[n * 64 + p + 32];
        buf[base + p]      = f2bf(a * c0 - b * s0);
        buf[base + p + 32] = f2bf(b * c1 + a * s1);
    }
}

// ---------------------------------------------------------------- flash attention v2
// Swapped QK^T (S^T = mfma(K,Q)) -> in-register softmax; P redistributed to PV
// A-fragments via shfl; K/V staged by global_load_lds with pre-swizzled source
// (chunk ^= row&7); 2-phase double buffer; grid (bh, qt) for XCD locality.
// 4 waves x 32 q-rows = 128 q-rows/block; KV tile = 64.
__global__ __launch_bounds__(256) void k_flash2(
        const short* __restrict__ qr, const short* __restrict__ kr, const short* __restrict__ vt,
        short* __restrict__ attn_out) {
    __shared__ short Ks[2][4096];   // [k=64][d=64] swizzled
    __shared__ short Vs[2][4096];   // [d=64][k=64] swizzled
    int bh = blockIdx.x, b = bh >> 3, h = bh & 7;
    int qt = blockIdx.y;
    int tid = threadIdx.x, wv = tid >> 6, ln = tid & 63;
    int lr = ln & 15, lg = ln >> 4;
    const short* Qb = qr + ((size_t)bh * N_ + qt * 128 + wv * 32) * HD;
    const short* Kb = kr + (size_t)bh * N_ * HD;
    const short* Vb = vt + (size_t)bh * HD * N_;

    // Q as B-operand fragments, pre-scaled by 1/sqrt(64)=0.125 (pow2: exact in bf16)
    bf16x8 qf[2][2];
#pragma unroll
    for (int qg = 0; qg < 2; qg++)
#pragma unroll
        for (int hf = 0; hf < 2; hf++) {
            bf16x8 raw = *(const bf16x8*)(Qb + (qg * 16 + lr) * 64 + hf * 32 + lg * 8);
            bf16x8 sc;
#pragma unroll
            for (int j = 0; j < 8; j++) sc[j] = f2bf(bf2f(raw[j]) * 0.125f);
            qf[qg][hf] = sc;
        }

    int srow = ln >> 3, cpos = ln & 7;

    float m_s[2] = {-1e30f, -1e30f}, l_s[2] = {0.f, 0.f};
    f32x4 ao[2][4] = {};

    // prologue stage
#pragma unroll
    for (int p = 0; p < 2; p++) {
        int rloc = p * 32 + wv * 8 + srow;
        int csrc = cpos ^ (rloc & 7);
        gload16(Kb + ((size_t)rloc) * 64 + csrc * 8, (void*)&Ks[0][(p * 32 + wv * 8) * 64]);
        gload16(Vb + ((size_t)rloc) * 1024 + csrc * 8, (void*)&Vs[0][(p * 32 + wv * 8) * 64]);
    }
    __syncthreads();

    for (int kt = 0; kt < 16; kt++) {
        int cur = kt & 1;
        if (kt < 15) {
            int nxt = cur ^ 1, ktn = kt + 1;
#pragma unroll
            for (int p = 0; p < 2; p++) {
                int rloc = p * 32 + wv * 8 + srow;
                int csrc = cpos ^ (rloc & 7);
                gload16(Kb + ((size_t)(ktn * 64 + rloc)) * 64 + csrc * 8,
                        (void*)&Ks[nxt][(p * 32 + wv * 8) * 64]);
                gload16(Vb + ((size_t)rloc) * 1024 + ktn * 64 + csrc * 8,
                        (void*)&Vs[nxt][(p * 32 + wv * 8) * 64]);
            }
        }

        // QK^T (swapped): sT[qg][f][r] = S[k=f*16+lg*4+r][q=lr] (scaled)
        f32x4 sT[2][4];
#pragma unroll
        for (int f = 0; f < 4; f++) {
            int r = f * 16 + lr;
            const short* kp = &Ks[cur][r * 64];
            bf16x8 ka  = *(const bf16x8*)(kp + ((lg ^ (r & 7)) * 8));
            bf16x8 kb2 = *(const bf16x8*)(kp + (((4 + lg) ^ (r & 7)) * 8));
#pragma unroll
            for (int qg = 0; qg < 2; qg++) {
                f32x4 s = {};
                s = MFMA16(ka, qf[qg][0], s);
                s = MFMA16(kb2, qf[qg][1], s);
                sT[qg][f] = s;
            }
        }

        bf16x8 pa[2][2];
#pragma unroll
        for (int qg = 0; qg < 2; qg++) {
            // row max over 16 in-lane + across lane groups (same lr)
            float mx = fmaxf(fmaxf(sT[qg][0][0], sT[qg][0][1]), fmaxf(sT[qg][0][2], sT[qg][0][3]));
#pragma unroll
            for (int f = 1; f < 4; f++)
                mx = fmaxf(mx, fmaxf(fmaxf(sT[qg][f][0], sT[qg][f][1]), fmaxf(sT[qg][f][2], sT[qg][f][3])));
            mx = fmaxf(mx, __shfl_xor(mx, 16, 64));
            mx = fmaxf(mx, __shfl_xor(mx, 32, 64));
            float mnew = fmaxf(m_s[qg], mx);
            float alpha = __expf(m_s[qg] - mnew);
            m_s[qg] = mnew;

            unsigned pk[4][2];
            float rsum = 0.f;
#pragma unroll
            for (int f = 0; f < 4; f++) {
                float p0 = __expf(sT[qg][f][0] - mnew);
                float p1 = __expf(sT[qg][f][1] - mnew);
                float p2 = __expf(sT[qg][f][2] - mnew);
                float p3 = __expf(sT[qg][f][3] - mnew);
                rsum += (p0 + p1) + (p2 + p3);
                pk[f][0] = pack2(p0, p1);
                pk[f][1] = pack2(p2, p3);
            }
            rsum += __shfl_xor(rsum, 16, 64);
            rsum += __shfl_xor(rsum, 32, 64);
            l_s[qg] = l_s[qg] * alpha + rsum;

            // rescale accumulator (alpha for q = lg*4+r lives in lane lg*4+r)
#pragma unroll
            for (int r2 = 0; r2 < 4; r2++) {
                float al = __shfl(alpha, lg * 4 + r2, 64);
#pragma unroll
                for (int dt = 0; dt < 4; dt++) ao[qg][dt][r2] *= al;
            }

            // redistribute P -> PV A-fragments.
            // lane(lr,g) frag0 word w: pk[g>>1][w&1] from lane lr+16*(2*(g&1)+(w>>1))
            int srcA = lr + ((lg & 1) << 5);
            int srcB = srcA + 16;
            int hiF = lg >> 1;
            unsigned w0, w1, w2, w3;
            union { unsigned u[4]; bf16x8 v; } c0, c1;
            { unsigned a = __shfl((int)pk[0][0], srcA, 64), bb = __shfl((int)pk[1][0], srcA, 64);
              w0 = hiF ? bb : a; }
            { unsigned a = __shfl((int)pk[0][1], srcA, 64), bb = __shfl((int)pk[1][1], srcA, 64);
              w1 = hiF ? bb : a; }
            { unsigned a = __shfl((int)pk[0][0], srcB, 64), bb = __shfl((int)pk[1][0], srcB, 64);
              w2 = hiF ? bb : a; }
            { unsigned a = __shfl((int)pk[0][1], srcB, 64), bb = __shfl((int)pk[1][1], srcB, 64);
              w3 = hiF ? bb : a; }
            c0.u[0] = w0; c0.u[1] = w1; c0.u[2] = w2; c0.u[3] = w3;
            { unsigned a = __shfl((int)pk[2][0], srcA, 64), bb = __shfl((int)pk[3][0], srcA, 64);
              w0 = hiF ? bb : a; }
            { unsigned a = __shfl((int)pk[2][1], srcA, 64), bb = __shfl((int)pk[3][1], srcA, 64);
              w1 = hiF ? bb : a; }
            { unsigned a = __shfl((int)pk[2][0], srcB, 64), bb = __shfl((int)pk[3][0], srcB, 64);
              w2 = hiF ? bb : a; }
            { unsigned a = __shfl((int)pk[2][1], srcB, 64), bb = __shfl((int)pk[3][1], srcB, 64);
              w3 = hiF ? bb : a; }
            c1.u[0] = w0; c1.u[1] = w1; c1.u[2] = w2; c1.u[3] = w3;
            pa[qg][0] = c0.v;
            pa[qg][1] = c1.v;
        }

        // PV: read each V fragment once, feed both q-groups
#pragma unroll
        for (int dt = 0; dt < 4; dt++) {
            int rr = dt * 16 + lr;
            const short* vp = &Vs[cur][rr * 64];
            bf16x8 v0 = *(const bf16x8*)(vp + ((lg ^ (rr & 7)) * 8));
            bf16x8 v1 = *(const bf16x8*)(vp + (((4 + lg) ^ (rr & 7)) * 8));
#pragma unroll
            for (int qg = 0; qg < 2; qg++) {
                ao[qg][dt] = MFMA16(pa[qg][0], v0, ao[qg][dt]);
                ao[qg][dt] = MFMA16(pa[qg][1], v1, ao[qg][dt]);
            }
        }
        __syncthreads();
    }

    // epilogue: normalize and store
#pragma unroll
    for (int qg = 0; qg < 2; qg++) {
#pragma unroll
        for (int r2 = 0; r2 < 4; r2++) {
            float lq = __shfl(l_s[qg], lg * 4 + r2, 64);
            float inv = 1.0f / lq;
            int qglob = qt * 128 + wv * 32 + qg * 16 + lg * 4 + r2;
            size_t ob = ((size_t)b * N_ + qglob) * 512 + h * 64;
#pragma unroll
            for (int dt = 0; dt < 4; dt++)
                attn_out[ob + dt * 16 + lr] = f2bf(ao[qg][dt][r2] * inv);
        }
    }
}

// ---------------------------------------------------------------- out proj (transposed: M=channels)
__global__ __launch_bounds__(256) void k_gemm_out(
        const short* __restrict__ A, const short* __restrict__ Bt,
        const float* __restrict__ x, const float* __restrict__ obias, float* __restrict__ out) {
    __shared__ short Asm[128 * 32];
    __shared__ short Bsm[128 * 32];
    int tid = threadIdx.x, wv = tid >> 6, ln = tid & 63;
    int wr = wv >> 1, wc = wv & 1, lr = ln & 15, lg = ln >> 4;
    const short* Ab = A + (size_t)blockIdx.y * 128 * 512;
    const short* Bb = Bt + (size_t)blockIdx.x * 128 * 512;
    f32x4 acc[4][4] = {};
    int srow = ln >> 2, sch = ln & 3;
    for (int kb = 0; kb < 512; kb += 32) {
        int r0 = wv * 32;
        const short* ga = Ab + (size_t)(r0 + srow) * 512 + kb + sch * 8;
        gload16(ga, (void*)(Asm + r0 * 32));
        gload16(ga + 16 * 512, (void*)(Asm + (r0 + 16) * 32));
        const short* gbp = Bb + (size_t)(r0 + srow) * 512 + kb + sch * 8;
        gload16(gbp, (void*)(Bsm + r0 * 32));
        gload16(gbp + 16 * 512, (void*)(Bsm + (r0 + 16) * 32));
        __syncthreads();
        bf16x8 af[4], bfr[4];
#pragma unroll
        for (int m = 0; m < 4; m++) af[m] = *(const bf16x8*)(Asm + (wr * 64 + m * 16 + lr) * 32 + lg * 8);
#pragma unroll
        for (int f = 0; f < 4; f++) bfr[f] = *(const bf16x8*)(Bsm + (wc * 64 + f * 16 + lr) * 32 + lg * 8);
#pragma unroll
        for (int m = 0; m < 4; m++)
#pragma unroll
            for (int f = 0; f < 4; f++)
                acc[m][f] = MFMA16(af[m], bfr[f], acc[m][f]);
        __syncthreads();
    }
    int cb = blockIdx.y * 128 + wr * 64, tb = blockIdx.x * 128 + wc * 64;
#pragma unroll
    for (int m = 0; m < 4; m++) {
#pragma unroll
        for (int f = 0; f < 4; f++) {
            int gt = tb + f * 16 + lr;
            int b = gt >> 10, n = gt & 1023;
#pragma unroll
            for (int r = 0; r < 4; r++) {
                int gc = cb + m * 16 + lg * 4 + r;
                size_t ad = ((size_t)b * C_ + gc) * N_ + n;
                out[ad] = acc[m][f][r] + obias[gc] + x[ad];
            }
        }
    }
}

// ---------------------------------------------------------------- launch
extern "C" void kernel_launch(void* const* d_in, const int* in_sizes, int n_in,
                              void* d_out, int out_size, void* d_ws, size_t ws_size,
                              hipStream_t stream) {
    const float* x     = (const float*)d_in[0];
    const float* temb  = (const float*)d_in[1];
    const float* tm_w1 = (const float*)d_in[2];
    const float* tm_b1 = (const float*)d_in[3];
    const float* tm_w2 = (const float*)d_in[4];
    const float* tm_b2 = (const float*)d_in[5];
    const float* qkv_w = (const float*)d_in[6];
    const float* out_w = (const float*)d_in[7];
    const float* out_b = (const float*)d_in[8];
    float* out = (float*)d_out;

    char* ws = (char*)d_ws;
    short* qkvwT  = (short*)(ws);                 // 1536*512*2  = 1,572,864
    short* outwT  = (short*)(ws + 1572864);       //  512*512*2  =   524,288
    float* cosT   = (float*)(ws + 2097152);       // 1024*64*4   =   262,144
    float* sinT   = (float*)(ws + 2359296);
    float* gb     = (float*)(ws + 2621440);       // 16*1024*4
    short* tokens = (short*)(ws + 2686976);       // 16384*512*2 = 16,777,216 (also attn_out)
    short* qr     = (short*)(ws + 19464192);      // 16,777,216
    short* kr     = (short*)(ws + 36241408);
    short* vt     = (short*)(ws + 53018624);      // end ~66.6 MB
    short* attn   = tokens;                        // tokens dead after k_gemm_qkv

    k_transpose_cast<<<dim3(3072), dim3(256), 0, stream>>>(qkv_w, qkvwT, 1536);
    k_transpose_cast<<<dim3(1024), dim3(256), 0, stream>>>(out_w, outwT, 512);
    k_rope_table<<<dim3(256), dim3(256), 0, stream>>>(cosT, sinT);
    k_time_mlp<<<dim3(16), dim3(512), 0, stream>>>(temb, tm_w1, tm_b1, tm_w2, tm_b2, gb);
    k_adacln<<<dim3(16, 16), dim3(256), 0, stream>>>(x, gb, tokens);
    k_gemm_qkv<<<dim3(12, 128), dim3(256), 0, stream>>>(tokens, qkvwT, qr, kr, vt);
    k_rope<<<dim3(4096), dim3(256), 0, stream>>>(qr, kr, cosT, sinT);
    k_flash2<<<dim3(128, 8), dim3(256), 0, stream>>>(qr, kr, vt, attn);
    k_gemm_out<<<dim3(128, 4), dim3(256), 0, stream>>>(outwT, attn, x, out_b, out);
}

// Round 4
// 222.500 us; speedup vs baseline: 1.3902x; 1.2421x over previous
//
#include <hip/hip_runtime.h>
#include <stdint.h>
#include <stddef.h>

// Problem constants
#define B_  16
#define C_  512
#define N_  1024    // H*W = 32*32
#define NH  8
#define HD  64

typedef __attribute__((ext_vector_type(8))) short bf16x8;
typedef __attribute__((ext_vector_type(4))) float f32x4;

__device__ __forceinline__ short f2bf(float f) {
    unsigned u = __builtin_bit_cast(unsigned, f);
    unsigned r = (u + 0x7fffu + ((u >> 16) & 1u)) >> 16;   // RNE
    return (short)(unsigned short)r;
}
__device__ __forceinline__ float bf2f(short s) {
    unsigned u = ((unsigned)(unsigned short)s) << 16;
    return __builtin_bit_cast(float, u);
}
__device__ __forceinline__ unsigned pack2(float lo, float hi) {
    return ((unsigned)(unsigned short)f2bf(hi) << 16) | (unsigned)(unsigned short)f2bf(lo);
}

#define MFMA16(a, b, c) __builtin_amdgcn_mfma_f32_16x16x32_bf16((a), (b), (c), 0, 0, 0)

typedef __attribute__((address_space(3))) unsigned int lds_u32;
typedef __attribute__((address_space(1))) unsigned int glb_u32;
// dest = wave-uniform LDS base + lane*16 (m104); global src is per-lane.
__device__ __forceinline__ void gload16(const void* g, void* l) {
    __builtin_amdgcn_global_load_lds((const glb_u32*)g, (lds_u32*)l, 16, 0, 0);
}

// ---------------------------------------------------------------- prep: weight casts + rope table
// bid < 3072: qkv_w (512,1536) -> qkvwT (1536,512) bf16
// bid < 4096: out_w (512,512)  -> outwT  (512,512)  bf16
// else      : packed rope table float4[n=1024][dq=32] = (cos_y, sin_y, cos_x, sin_x)
__global__ void k_prep(const float* __restrict__ qkv_w, const float* __restrict__ out_w,
                       short* __restrict__ qkvwT, short* __restrict__ outwT,
                       float4* __restrict__ ropetab) {
    int bid = blockIdx.x, tid = threadIdx.x;
    if (bid < 3072) {
        int idx = bid * 256 + tid; int j = idx >> 9, k = idx & 511;
        qkvwT[idx] = f2bf(qkv_w[(size_t)k * 1536 + j]);
    } else if (bid < 4096) {
        int idx = (bid - 3072) * 256 + tid; int j = idx >> 9, k = idx & 511;
        outwT[idx] = f2bf(out_w[(size_t)k * 512 + j]);
    } else {
        int idx = (bid - 4096) * 256 + tid;       // 32768 entries
        int n = idx >> 5, dq = idx & 31, i = dq & 15;
        float w = powf(100.0f, -(float)i * (1.0f / 16.0f));
        float y = (float)(n >> 5), xx = (float)(n & 31);
        ropetab[idx] = make_float4(cosf(y * w), sinf(y * w), cosf(xx * w), sinf(xx * w));
    }
}

// ---------------------------------------------------------------- time MLP
__global__ __launch_bounds__(512) void k_time_mlp(
        const float* __restrict__ temb, const float* __restrict__ w1, const float* __restrict__ b1,
        const float* __restrict__ w2, const float* __restrict__ b2, float* __restrict__ gbout) {
    __shared__ float tl[512];
    __shared__ float hl[512];
    int b = blockIdx.x, tid = threadIdx.x;
    tl[tid] = temb[b * 512 + tid];
    __syncthreads();
    float acc = b1[tid];
#pragma unroll 8
    for (int k = 0; k < 512; k++) acc += tl[k] * w1[(size_t)k * 512 + tid];
    hl[tid] = acc / (1.0f + __expf(-acc));              // silu
    __syncthreads();
    float a0 = b2[tid], a1 = b2[tid + 512];
#pragma unroll 8
    for (int k = 0; k < 512; k++) {
        float hk = hl[k];
        a0 += hk * w2[(size_t)k * 1024 + tid];
        a1 += hk * w2[(size_t)k * 1024 + tid + 512];
    }
    gbout[b * 1024 + tid] = a0;
    gbout[b * 1024 + 512 + tid] = a1;
}

// ---------------------------------------------------------------- AdaCLN -> tokens bf16 (B,N,C)
__global__ __launch_bounds__(256) void k_adacln(
        const float* __restrict__ x, const float* __restrict__ gb, short* __restrict__ tokens) {
    int b = blockIdx.y, n0 = blockIdx.x * 64;
    int tid = threadIdx.x, pix = tid & 63, sl = tid >> 6;
    const float* xb = x + (size_t)b * C_ * N_;
    __shared__ float rs[4][64], rq[4][64], mean_s[64], rstd_s[64];
    __shared__ float xs[64][65];

    float sum = 0.f, sq = 0.f;
    for (int ci = 0; ci < 128; ci++) {
        int c = sl * 128 + ci;
        float v = xb[(size_t)c * N_ + n0 + pix];
        sum += v; sq += v * v;
    }
    rs[sl][pix] = sum; rq[sl][pix] = sq;
    __syncthreads();
    if (tid < 64) {
        float s1 = rs[0][tid] + rs[1][tid] + rs[2][tid] + rs[3][tid];
        float s2 = rq[0][tid] + rq[1][tid] + rq[2][tid] + rq[3][tid];
        float mu = s1 * (1.0f / 512.0f);
        float var = s2 * (1.0f / 512.0f) - mu * mu;
        mean_s[tid] = mu;
        rstd_s[tid] = rsqrtf(var + 1e-6f);
    }
    const float* gam = gb + b * 1024;
    const float* bet = gam + 512;
    int ch = tid & 7;
    for (int ct = 0; ct < 8; ct++) {
        __syncthreads();
        for (int it = 0; it < 16; it++) {
            int cl = it * 4 + sl;
            xs[cl][pix] = xb[(size_t)(ct * 64 + cl) * N_ + n0 + pix];
        }
        __syncthreads();
#pragma unroll
        for (int pp = 0; pp < 2; pp++) {
            int p = pp * 32 + (tid >> 3);
            float mu = mean_s[p], rt = rstd_s[p];
            bf16x8 ov;
#pragma unroll
            for (int j = 0; j < 8; j++) {
                int c = ct * 64 + ch * 8 + j;
                float v = (xs[ch * 8 + j][p] - mu) * rt * (1.0f + gam[c]) + bet[c];
                ov[j] = f2bf(v);
            }
            *(bf16x8*)(tokens + ((size_t)(b * N_ + n0 + p)) * C_ + ct * 64 + ch * 8) = ov;
        }
    }
}

// ---------------------------------------------------------------- QKV GEMM + fused RoPE
// A = tokens (16384,512), Bt = qkv_wT (1536,512). sec = blockIdx.x>>2 (0=q,1=k,2=v).
// q/k epilogue applies RoPE via packed table; v scatters to v^T (B,h,d,N).
__global__ __launch_bounds__(256) void k_gemm_qkv(
        const short* __restrict__ A, const short* __restrict__ Bt,
        const float4* __restrict__ ropetab,
        short* __restrict__ qr, short* __restrict__ kr, short* __restrict__ vt) {
    __shared__ short Asm[128 * 32];
    __shared__ short Bsm[128 * 32];
    int tid = threadIdx.x, wv = tid >> 6, ln = tid & 63;
    int wr = wv >> 1, wc = wv & 1, lr = ln & 15, lg = ln >> 4;
    const short* Ab = A + (size_t)blockIdx.y * 128 * 512;
    const short* Bb = Bt + (size_t)blockIdx.x * 128 * 512;
    f32x4 acc[4][4] = {};
    int srow = ln >> 2, sch = ln & 3;
    for (int kb = 0; kb < 512; kb += 32) {
        int r0 = wv * 32;
        const short* ga = Ab + (size_t)(r0 + srow) * 512 + kb + sch * 8;
        gload16(ga, (void*)(Asm + r0 * 32));
        gload16(ga + 16 * 512, (void*)(Asm + (r0 + 16) * 32));
        const short* gbp = Bb + (size_t)(r0 + srow) * 512 + kb + sch * 8;
        gload16(gbp, (void*)(Bsm + r0 * 32));
        gload16(gbp + 16 * 512, (void*)(Bsm + (r0 + 16) * 32));
        __syncthreads();
        bf16x8 af[4], bfr[4];
#pragma unroll
        for (int m = 0; m < 4; m++) af[m] = *(const bf16x8*)(Asm + (wr * 64 + m * 16 + lr) * 32 + lg * 8);
#pragma unroll
        for (int f = 0; f < 4; f++) bfr[f] = *(const bf16x8*)(Bsm + (wc * 64 + f * 16 + lr) * 32 + lg * 8);
#pragma unroll
        for (int m = 0; m < 4; m++)
#pragma unroll
            for (int f = 0; f < 4; f++)
                acc[m][f] = MFMA16(af[m], bfr[f], acc[m][f]);
        __syncthreads();
    }
    int mbase = blockIdx.y * 128;
    int sec = blockIdx.x >> 2;
    int h = (2 * blockIdx.x + wc) & 7;
    if (sec < 2) {
        short* dst0 = (sec == 0) ? qr : kr;
#pragma unroll
        for (int m = 0; m < 4; m++) {
            int gmb = mbase + wr * 64 + m * 16 + lg * 4;
#pragma unroll
            for (int r = 0; r < 4; r++) {
                int gm = gmb + r; int b = gm >> 10, n = gm & 1023;
                short* rowp = dst0 + (((size_t)b * NH + h) * N_ + n) * HD;
                const float4* tr = ropetab + n * 32;
#pragma unroll
                for (int f2 = 0; f2 < 2; f2++) {
                    int d_lo = f2 * 16 + lr;
                    float4 t = tr[d_lo];
                    float a = acc[m][f2][r], bb2 = acc[m][f2 + 2][r];
                    rowp[d_lo]      = f2bf(a * t.x - bb2 * t.y);
                    rowp[d_lo + 32] = f2bf(bb2 * t.z + a * t.w);
                }
            }
        }
    } else {
#pragma unroll
        for (int m = 0; m < 4; m++) {
            int gmb = mbase + wr * 64 + m * 16 + lg * 4;
#pragma unroll
            for (int f = 0; f < 4; f++) {
                int d = f * 16 + lr;
#pragma unroll
                for (int r = 0; r < 4; r++) {
                    int gm = gmb + r; int b = gm >> 10, n = gm & 1023;
                    vt[(((size_t)b * NH + h) * HD + d) * N_ + n] = f2bf(acc[m][f][r]);
                }
            }
        }
    }
}

// ---------------------------------------------------------------- flash attention v3
// Swapped QK^T (S^T = mfma(K,Q)) -> lane-local softmax (q = lane&15);
// P^T transposed through wave-private LDS (2-way-free bank mapping);
// fully-transposed PV: O^T = mfma(V^T-frag, P^T-frag) -> alpha/l lane-local,
// vectorized 8B output stores. K/V via global_load_lds, XOR-swizzled source,
// 2-phase double buffer. 4 waves x 32 q-rows; KV tile 64; grid (bh, qt).
__global__ __launch_bounds__(256) void k_flash3(
        const short* __restrict__ qr, const short* __restrict__ kr, const short* __restrict__ vt,
        short* __restrict__ attn_out) {
    __shared__ short Ks[2][4096];        // [k=64][d=64] chunk-swizzled
    __shared__ short Vs[2][4096];        // [d=64][k=64] chunk-swizzled
    __shared__ unsigned Ps[4][32][32];   // per-wave [kp=32][col=32] u32 (2 bf16)
    int bh = blockIdx.x, b = bh >> 3, h = bh & 7;
    int qt = blockIdx.y;
    int tid = threadIdx.x, wv = tid >> 6, ln = tid & 63;
    int lr = ln & 15, lg = ln >> 4;
    const short* Qb = qr + ((size_t)bh * N_ + qt * 128 + wv * 32) * HD;
    const short* Kb = kr + (size_t)bh * N_ * HD;
    const short* Vb = vt + (size_t)bh * HD * N_;

    // Q as B-operand fragments, pre-scaled by 1/8 (exact in bf16)
    bf16x8 qf[2][2];
#pragma unroll
    for (int qg = 0; qg < 2; qg++)
#pragma unroll
        for (int hf = 0; hf < 2; hf++) {
            bf16x8 raw = *(const bf16x8*)(Qb + (qg * 16 + lr) * 64 + hf * 32 + lg * 8);
            bf16x8 sc;
#pragma unroll
            for (int j = 0; j < 8; j++) sc[j] = f2bf(bf2f(raw[j]) * 0.125f);
            qf[qg][hf] = sc;
        }

    int srow = ln >> 3, cpos = ln & 7;
    unsigned* PsW = &Ps[wv][0][0];

    float m_s[2] = {-1e30f, -1e30f}, l_s[2] = {0.f, 0.f};
    f32x4 ao[2][4] = {};

    // prologue stage
#pragma unroll
    for (int p = 0; p < 2; p++) {
        int rloc = p * 32 + wv * 8 + srow;
        int csrc = cpos ^ (rloc & 7);
        gload16(Kb + ((size_t)rloc) * 64 + csrc * 8, (void*)&Ks[0][(p * 32 + wv * 8) * 64]);
        gload16(Vb + ((size_t)rloc) * 1024 + csrc * 8, (void*)&Vs[0][(p * 32 + wv * 8) * 64]);
    }
    __syncthreads();

    for (int kt = 0; kt < 16; kt++) {
        int cur = kt & 1;
        if (kt < 15) {
            int nxt = cur ^ 1, ktn = kt + 1;
#pragma unroll
            for (int p = 0; p < 2; p++) {
                int rloc = p * 32 + wv * 8 + srow;
                int csrc = cpos ^ (rloc & 7);
                gload16(Kb + ((size_t)(ktn * 64 + rloc)) * 64 + csrc * 8,
                        (void*)&Ks[nxt][(p * 32 + wv * 8) * 64]);
                gload16(Vb + ((size_t)rloc) * 1024 + ktn * 64 + csrc * 8,
                        (void*)&Vs[nxt][(p * 32 + wv * 8) * 64]);
            }
        }

        // QK^T (swapped): sT[qg][f][r] = S^T[k = f*16+lg*4+r][q = qg*16+lr] (scaled)
        f32x4 sT[2][4];
#pragma unroll
        for (int f = 0; f < 4; f++) {
            int r = f * 16 + lr;
            const short* kp = &Ks[cur][r * 64];
            bf16x8 ka  = *(const bf16x8*)(kp + ((lg ^ (r & 7)) * 8));
            bf16x8 kb2 = *(const bf16x8*)(kp + (((4 + lg) ^ (r & 7)) * 8));
#pragma unroll
            for (int qg = 0; qg < 2; qg++) {
                f32x4 s = {};
                s = MFMA16(ka, qf[qg][0], s);
                s = MFMA16(kb2, qf[qg][1], s);
                sT[qg][f] = s;
            }
        }

        // softmax (all lane-local except two xor-reduces) + P^T into LDS
#pragma unroll
        for (int qg = 0; qg < 2; qg++) {
            float mx = fmaxf(fmaxf(sT[qg][0][0], sT[qg][0][1]), fmaxf(sT[qg][0][2], sT[qg][0][3]));
#pragma unroll
            for (int f = 1; f < 4; f++)
                mx = fmaxf(mx, fmaxf(fmaxf(sT[qg][f][0], sT[qg][f][1]), fmaxf(sT[qg][f][2], sT[qg][f][3])));
            mx = fmaxf(mx, __shfl_xor(mx, 16, 64));
            mx = fmaxf(mx, __shfl_xor(mx, 32, 64));
            float mnew = fmaxf(m_s[qg], mx);
            float alpha = __expf(m_s[qg] - mnew);
            m_s[qg] = mnew;

            float rsum = 0.f;
            // write base: kp0 = f*8 + lg*2, col = lr + 16*((lg>>1)^qg)
            unsigned* wp0 = PsW + lg * 64 + lr + ((((unsigned)lg >> 1) ^ qg) << 4);
#pragma unroll
            for (int f = 0; f < 4; f++) {
                float p0 = __expf(sT[qg][f][0] - mnew);
                float p1 = __expf(sT[qg][f][1] - mnew);
                float p2 = __expf(sT[qg][f][2] - mnew);
                float p3 = __expf(sT[qg][f][3] - mnew);
                rsum += (p0 + p1) + (p2 + p3);
                unsigned* wp = wp0 + f * 256;        // (f*8)*32
                wp[0]  = pack2(p0, p1);              // kp0
                wp[32] = pack2(p2, p3);              // kp0+1
            }
            rsum += __shfl_xor(rsum, 16, 64);
            rsum += __shfl_xor(rsum, 32, 64);
            l_s[qg] = l_s[qg] * alpha + rsum;

            // rescale accumulator: alpha is lane-local (this lane's q-column)
#pragma unroll
            for (int dt = 0; dt < 4; dt++) ao[qg][dt] *= alpha;
        }

        // read P^T fragments (B-operand): kp = kb*16 + lg*4 + w, col = lr + 16*((lg&1)^qg)
        union U4 { unsigned u[4]; bf16x8 v; };
        U4 pb[2][2];
#pragma unroll
        for (int qg = 0; qg < 2; qg++) {
#pragma unroll
            for (int kb = 0; kb < 2; kb++) {
                unsigned* rp = PsW + kb * 512 + lg * 128 + lr + ((((unsigned)lg & 1) ^ qg) << 4);
                pb[qg][kb].u[0] = rp[0];
                pb[qg][kb].u[1] = rp[32];
                pb[qg][kb].u[2] = rp[64];
                pb[qg][kb].u[3] = rp[96];
            }
        }

        // PV: O^T += V^T-frag x P^T-frag
#pragma unroll
        for (int dt = 0; dt < 4; dt++) {
            int rr = dt * 16 + lr;
            const short* vp = &Vs[cur][rr * 64];
            bf16x8 va0 = *(const bf16x8*)(vp + ((lg ^ (rr & 7)) * 8));
            bf16x8 va1 = *(const bf16x8*)(vp + (((4 + lg) ^ (rr & 7)) * 8));
#pragma unroll
            for (int qg = 0; qg < 2; qg++) {
                ao[qg][dt] = MFMA16(va0, pb[qg][0].v, ao[qg][dt]);
                ao[qg][dt] = MFMA16(va1, pb[qg][1].v, ao[qg][dt]);
            }
        }
        __syncthreads();
    }

    // epilogue: normalize (lane-local l) and store 8B chunks
#pragma unroll
    for (int qg = 0; qg < 2; qg++) {
        float inv = 1.0f / l_s[qg];
        int qglob = qt * 128 + wv * 32 + qg * 16 + lr;
        size_t ob = ((size_t)b * N_ + qglob) * 512 + h * 64 + lg * 4;
#pragma unroll
        for (int dt = 0; dt < 4; dt++) {
            uint2 val;
            val.x = pack2(ao[qg][dt][0] * inv, ao[qg][dt][1] * inv);
            val.y = pack2(ao[qg][dt][2] * inv, ao[qg][dt][3] * inv);
            *(uint2*)(attn_out + ob + dt * 16) = val;
        }
    }
}

// ---------------------------------------------------------------- out proj (transposed: M=channels)
__global__ __launch_bounds__(256) void k_gemm_out(
        const short* __restrict__ A, const short* __restrict__ Bt,
        const float* __restrict__ x, const float* __restrict__ obias, float* __restrict__ out) {
    __shared__ short Asm[128 * 32];
    __shared__ short Bsm[128 * 32];
    int tid = threadIdx.x, wv = tid >> 6, ln = tid & 63;
    int wr = wv >> 1, wc = wv & 1, lr = ln & 15, lg = ln >> 4;
    const short* Ab = A + (size_t)blockIdx.y * 128 * 512;
    const short* Bb = Bt + (size_t)blockIdx.x * 128 * 512;
    f32x4 acc[4][4] = {};
    int srow = ln >> 2, sch = ln & 3;
    for (int kb = 0; kb < 512; kb += 32) {
        int r0 = wv * 32;
        const short* ga = Ab + (size_t)(r0 + srow) * 512 + kb + sch * 8;
        gload16(ga, (void*)(Asm + r0 * 32));
        gload16(ga + 16 * 512, (void*)(Asm + (r0 + 16) * 32));
        const short* gbp = Bb + (size_t)(r0 + srow) * 512 + kb + sch * 8;
        gload16(gbp, (void*)(Bsm + r0 * 32));
        gload16(gbp + 16 * 512, (void*)(Bsm + (r0 + 16) * 32));
        __syncthreads();
        bf16x8 af[4], bfr[4];
#pragma unroll
        for (int m = 0; m < 4; m++) af[m] = *(const bf16x8*)(Asm + (wr * 64 + m * 16 + lr) * 32 + lg * 8);
#pragma unroll
        for (int f = 0; f < 4; f++) bfr[f] = *(const bf16x8*)(Bsm + (wc * 64 + f * 16 + lr) * 32 + lg * 8);
#pragma unroll
        for (int m = 0; m < 4; m++)
#pragma unroll
            for (int f = 0; f < 4; f++)
                acc[m][f] = MFMA16(af[m], bfr[f], acc[m][f]);
        __syncthreads();
    }
    int cb = blockIdx.y * 128 + wr * 64, tb = blockIdx.x * 128 + wc * 64;
#pragma unroll
    for (int m = 0; m < 4; m++) {
#pragma unroll
        for (int f = 0; f < 4; f++) {
            int gt = tb + f * 16 + lr;
            int b = gt >> 10, n = gt & 1023;
#pragma unroll
            for (int r = 0; r < 4; r++) {
                int gc = cb + m * 16 + lg * 4 + r;
                size_t ad = ((size_t)b * C_ + gc) * N_ + n;
                out[ad] = acc[m][f][r] + obias[gc] + x[ad];
            }
        }
    }
}

// ---------------------------------------------------------------- launch
extern "C" void kernel_launch(void* const* d_in, const int* in_sizes, int n_in,
                              void* d_out, int out_size, void* d_ws, size_t ws_size,
                              hipStream_t stream) {
    const float* x     = (const float*)d_in[0];
    const float* temb  = (const float*)d_in[1];
    const float* tm_w1 = (const float*)d_in[2];
    const float* tm_b1 = (const float*)d_in[3];
    const float* tm_w2 = (const float*)d_in[4];
    const float* tm_b2 = (const float*)d_in[5];
    const float* qkv_w = (const float*)d_in[6];
    const float* out_w = (const float*)d_in[7];
    const float* out_b = (const float*)d_in[8];
    float* out = (float*)d_out;

    char* ws = (char*)d_ws;
    short*  qkvwT  = (short*)(ws);                 // 1536*512*2  = 1,572,864
    short*  outwT  = (short*)(ws + 1572864);       //  512*512*2  =   524,288
    float4* ropetab= (float4*)(ws + 2097152);      // 1024*32*16  =   524,288
    float*  gb     = (float*)(ws + 2621440);       // 16*1024*4
    short*  tokens = (short*)(ws + 2686976);       // 16384*512*2 = 16,777,216 (also attn_out)
    short*  qr     = (short*)(ws + 19464192);      // 16,777,216
    short*  kr     = (short*)(ws + 36241408);
    short*  vt     = (short*)(ws + 53018624);      // end ~66.6 MB
    short*  attn   = tokens;                        // tokens dead after k_gemm_qkv

    k_prep<<<dim3(4224), dim3(256), 0, stream>>>(qkv_w, out_w, qkvwT, outwT, ropetab);
    k_time_mlp<<<dim3(16), dim3(512), 0, stream>>>(temb, tm_w1, tm_b1, tm_w2, tm_b2, gb);
    k_adacln<<<dim3(16, 16), dim3(256), 0, stream>>>(x, gb, tokens);
    k_gemm_qkv<<<dim3(12, 128), dim3(256), 0, stream>>>(tokens, qkvwT, ropetab, qr, kr, vt);
    k_flash3<<<dim3(128, 8), dim3(256), 0, stream>>>(qr, kr, vt, attn);
    k_gemm_out<<<dim3(128, 4), dim3(256), 0, stream>>>(outwT, attn, x, out_b, out);
}